// Round 10
// baseline (133.322 us; speedup 1.0000x reference)
//
#include <hip/hip_runtime.h>
#include <hip/hip_bf16.h>
#include <string.h>

#define BATCH 8
#define DM 1024
#define NS 64
#define SL 2048
#define NC 32
#define TC 64

typedef __attribute__((ext_vector_type(8))) short bf16x8;
typedef __attribute__((ext_vector_type(4))) float f32x4;
typedef float v2f __attribute__((ext_vector_type(2)));

__device__ inline unsigned short f2bf(float f) {
    union { float f; unsigned u; } v; v.f = f;
    return (unsigned short)((v.u + 0x7fffu + ((v.u >> 16) & 1u)) >> 16);
}
__device__ inline float bf2f(unsigned short h) {
    return __uint_as_float(((unsigned)h) << 16);
}
static __device__ inline v2f bfpair_to_v2f(unsigned int p) {
    unsigned int lo = p << 16, hi = p & 0xffff0000u;
    v2f r; r.x = __uint_as_float(lo); r.y = __uint_as_float(hi); return r;
}

// ws layout (bytes):
//  BuT bf16 [B][SL][NS]      off  0MB  (2MB)
//  CuT bf16 [B][SL][NS]      off  2MB  (2MB)
//  BT  bf16 [NS][DM]         off  4MB  (128KB) ; CT right after
//  G   bf16 [B][NC][64][64]  off  5MB  (2MB)
//  Bv  bf16 [B][NC][64][64]  off  7MB  (2MB)
//  Wc  bf16 [B][NC][64][64]  off  9MB  (2MB)
//  E   bf16 [B][NC][DM][NS]  off 11MB  (32MB)   -> total 43MB

// ---------- kernel 0: transpose B,C -> BT,CT bf16 [n][d] ----------
__global__ __launch_bounds__(256) void k_prep(const float* __restrict__ Bm,
                                              const float* __restrict__ Cm,
                                              unsigned short* __restrict__ BT,
                                              unsigned short* __restrict__ CT)
{
    __shared__ float sT[64][65];
    const float* src = blockIdx.y ? Cm : Bm;
    unsigned short* dst = blockIdx.y ? CT : BT;
    const int d0 = blockIdx.x * 64, t = threadIdx.x;
    {
        int r = t >> 2, f = (t & 3) * 16;
#pragma unroll
        for (int i = 0; i < 4; i++) {
            float4 v = *(const float4*)&src[(size_t)(d0 + r) * NS + f + i * 4];
            sT[r][f + i * 4 + 0] = v.x; sT[r][f + i * 4 + 1] = v.y;
            sT[r][f + i * 4 + 2] = v.z; sT[r][f + i * 4 + 3] = v.w;
        }
    }
    __syncthreads();
    {
        int n = t >> 2, dq = (t & 3) * 16;
        unsigned pk[8];
#pragma unroll
        for (int k = 0; k < 8; k++) {
            unsigned short a = f2bf(sT[dq + 2 * k][n]);
            unsigned short bb = f2bf(sT[dq + 2 * k + 1][n]);
            pk[k] = (unsigned)a | ((unsigned)bb << 16);
        }
        uint4 v0 = { pk[0], pk[1], pk[2], pk[3] };
        uint4 v1 = { pk[4], pk[5], pk[6], pk[7] };
        *(uint4*)&dst[(size_t)n * DM + d0 + dq] = v0;
        *(uint4*)&dst[(size_t)n * DM + d0 + dq + 8] = v1;
    }
}

// ---------- kernel 1: Bu/Cu projections via MFMA (reg-prefetch pipeline) ----------
// grid (SL/32, B), 256 thr. out[l][n] = sum_d u[d][l] * BC[n][d]
__global__ __launch_bounds__(256) void k_proj(const float* __restrict__ u,
                                              const unsigned short* __restrict__ BC, // [128][DM]
                                              unsigned short* __restrict__ BuT,
                                              unsigned short* __restrict__ CuT)
{
    __shared__ unsigned short sA[32 * 64];   // [l][d] swz
    __shared__ unsigned short sB[128 * 64];  // [n][d] swz
    const int b = blockIdx.y, l0 = blockIdx.x * 32, t = threadIdx.x;
    const int lane = t & 63, w = t >> 6, g = lane >> 4, m15 = lane & 15;
    const int rr = t >> 3, c8 = t & 7;

    float4 vU[2]; uint4 vB[4];
#pragma unroll
    for (int p = 0; p < 2; p++)
        vU[p] = *(const float4*)&u[((size_t)b * DM + p * 32 + rr) * SL + l0 + c8 * 4];
#pragma unroll
    for (int p = 0; p < 4; p++)
        vB[p] = *(const uint4*)(BC + (size_t)(p * 32 + rr) * DM + c8 * 8);

    f32x4 acc[2][2];
#pragma unroll
    for (int i = 0; i < 2; i++)
#pragma unroll
        for (int j = 0; j < 2; j++) acc[i][j] = (f32x4){0.f, 0.f, 0.f, 0.f};

#pragma unroll 1
    for (int d0 = 0; d0 < DM; d0 += 64) {
        __syncthreads();                 // prior-iter readers done
        // write staged regs -> LDS
#pragma unroll
        for (int p = 0; p < 2; p++) {
            int dd = p * 32 + rr, l = c8 * 4;
            float4 v = vU[p];
            sA[(l + 0) * 64 + (((dd >> 3) ^ ((l + 0) & 7)) * 8) + (dd & 7)] = f2bf(v.x);
            sA[(l + 1) * 64 + (((dd >> 3) ^ ((l + 1) & 7)) * 8) + (dd & 7)] = f2bf(v.y);
            sA[(l + 2) * 64 + (((dd >> 3) ^ ((l + 2) & 7)) * 8) + (dd & 7)] = f2bf(v.z);
            sA[(l + 3) * 64 + (((dd >> 3) ^ ((l + 3) & 7)) * 8) + (dd & 7)] = f2bf(v.w);
        }
#pragma unroll
        for (int p = 0; p < 4; p++) {
            int row = p * 32 + rr;
            *(uint4*)&sB[row * 64 + ((c8 ^ (row & 7)) * 8)] = vB[p];
        }
        __syncthreads();
        if (d0 + 64 < DM) {              // issue next-tile loads; latency hides under MFMAs
#pragma unroll
            for (int p = 0; p < 2; p++)
                vU[p] = *(const float4*)&u[((size_t)b * DM + d0 + 64 + p * 32 + rr) * SL + l0 + c8 * 4];
#pragma unroll
            for (int p = 0; p < 4; p++)
                vB[p] = *(const uint4*)(BC + (size_t)(p * 32 + rr) * DM + d0 + 64 + c8 * 8);
        }
#pragma unroll
        for (int ks = 0; ks < 2; ks++) {
            bf16x8 af[2], bf[2];
#pragma unroll
            for (int mt = 0; mt < 2; mt++) {
                int r = mt * 16 + m15;
                af[mt] = *(const bf16x8*)&sA[r * 64 + (((ks * 4 + g) ^ (r & 7)) * 8)];
            }
#pragma unroll
            for (int nt = 0; nt < 2; nt++) {
                int r = w * 32 + nt * 16 + m15;
                bf[nt] = *(const bf16x8*)&sB[r * 64 + (((ks * 4 + g) ^ (r & 7)) * 8)];
            }
#pragma unroll
            for (int mt = 0; mt < 2; mt++)
#pragma unroll
                for (int nt = 0; nt < 2; nt++)
                    acc[mt][nt] = __builtin_amdgcn_mfma_f32_16x16x32_bf16(af[mt], bf[nt], acc[mt][nt], 0, 0, 0);
        }
    }
    // epilogue: C[m=l][n=wn]
#pragma unroll
    for (int mt = 0; mt < 2; mt++)
#pragma unroll
        for (int nt = 0; nt < 2; nt++) {
            int wn = w * 32 + nt * 16 + m15;
            unsigned short* dst = (wn < 64) ? BuT : CuT;
            int n = wn & 63;
#pragma unroll
            for (int r = 0; r < 4; r++) {
                int l = l0 + mt * 16 + g * 4 + r;
                dst[((size_t)b * SL + l) * NS + n] = f2bf(acc[mt][nt][r]);
            }
        }
}

// ---------- kernel 2: per-chunk G / Bv / Wc via power table ----------
__global__ __launch_bounds__(256) void k_g(const float* __restrict__ A,
                                           const unsigned short* __restrict__ BuT,
                                           const unsigned short* __restrict__ CuT,
                                           unsigned short* __restrict__ Gw,
                                           unsigned short* __restrict__ Bvw,
                                           unsigned short* __restrict__ Wcw)
{
    __shared__ unsigned short sCu[64 * 64];    // [l][n] linear (uniform-row reads)
    __shared__ unsigned short sBu[8 * 64 * 8]; // [q][l][8] subtiled
    __shared__ unsigned short sP[8 * 66 * 8];  // [q][dl 0..64][8] subtiled
    __shared__ unsigned short sTb[64 * 66];    // [n][l] transpose buffer (pad 66)
    const int cc = blockIdx.x, b = cc >> 5, c = cc & 31;
    const int t = threadIdx.x, lane = t & 63;
    const int l0 = c * TC;
    const size_t gbase = (size_t)cc * 4096;

    {
        const unsigned short* srcC = CuT + ((size_t)b * SL + l0) * NS;
        const unsigned short* srcB = BuT + ((size_t)b * SL + l0) * NS;
#pragma unroll
        for (int p = 0; p < 2; p++) {
            int idx = p * 256 + t;
            int r = idx >> 3, q8 = idx & 7;
            uint4 vc = *(const uint4*)(srcC + (size_t)r * NS + q8 * 8);
            *(uint4*)&sCu[r * 64 + q8 * 8] = vc;
            uint4 vb = *(const uint4*)(srcB + (size_t)r * NS + q8 * 8);
            *(uint4*)&sBu[(q8 * 64 + r) * 8] = vb;
        }
    }
    {
        int n = t & 63;
        float an = A[n * NS + n];
        int q = n >> 3, n7 = n & 7;
#pragma unroll 1
        for (int dl = (t >> 6) * 17; dl < (t >> 6) * 17 + 17 && dl <= 64; dl++)
            sP[(q * 66 + dl) * 8 + n7] = f2bf(__powf(an, (float)dl));
    }
    __syncthreads();

#pragma unroll 1
    for (int r = 0; r < 16; r++) {
        int idx = r * 256 + t;
        int l = idx >> 6;             // wave-uniform
        int lp = lane;
        int dl = l - lp;
        float acc = 0.f;
        if (dl >= 0) {
#pragma unroll
            for (int q = 0; q < 8; q++) {
                bf16x8 cu = *(const bf16x8*)&sCu[l * 64 + q * 8];
                bf16x8 bu = *(const bf16x8*)&sBu[(q * 64 + lp) * 8];
                bf16x8 pp = *(const bf16x8*)&sP[(q * 66 + dl) * 8];
#pragma unroll
                for (int j = 0; j < 8; j++)
                    acc = fmaf(bf2f((unsigned short)cu[j]) * bf2f((unsigned short)bu[j]),
                               bf2f((unsigned short)pp[j]), acc);
            }
        }
        Gw[gbase + l * 64 + lp] = (dl >= 0) ? f2bf(acc) : (unsigned short)0;
    }

#pragma unroll 1
    for (int r = 0; r < 16; r++) {
        int idx = r * 256 + t;
        int l = idx >> 6;
        int n = lane, q = n >> 3, n7 = n & 7;
        float cu = bf2f(sCu[l * 64 + n]);
        float pv = bf2f(sP[(q * 66 + (l + 1)) * 8 + n7]);
        Wcw[gbase + l * 64 + n] = f2bf(cu * pv);
    }

#pragma unroll 1
    for (int r = 0; r < 16; r++) {
        int idx = r * 256 + t;
        int l = idx >> 6;
        int n = lane, q = n >> 3, n7 = n & 7;
        float bu = bf2f(sBu[(q * 64 + l) * 8 + n7]);
        float pv = bf2f(sP[(q * 66 + (63 - l)) * 8 + n7]);
        sTb[n * 66 + l] = f2bf(bu * pv);
    }
    __syncthreads();
#pragma unroll 1
    for (int r = 0; r < 16; r++) {
        int idx = r * 256 + t;
        int n = idx >> 6;
        int l = lane;
        Bvw[gbase + n * 64 + l] = sTb[n * 66 + l];
    }
}

// ---------- kernel 3: E = u @ Bv^T via MFMA ----------
// grid (4 dslab, NC, B), 256 thr. E[d][n] = sum_l' u[d][l'] Bv[n][l']
__global__ __launch_bounds__(256) void k_state(const float* __restrict__ u,
                                               const unsigned short* __restrict__ Bvw,
                                               unsigned short* __restrict__ Ew)
{
    __shared__ unsigned short sU[256 * 64];   // 32KB
    __shared__ unsigned short sV[64 * 64];    // 8KB
    const int slab = blockIdx.x, c = blockIdx.y, b = blockIdx.z;
    const int d0 = slab * 256, l0 = c * TC;
    const int t = threadIdx.x, lane = t & 63, w = t >> 6, g = lane >> 4, m15 = lane & 15;

    {
        size_t gbase = ((size_t)(b * NC + c)) * 4096;
        int rr = t >> 3, c8 = t & 7;
#pragma unroll
        for (int p = 0; p < 2; p++) {
            int r = p * 32 + rr;
            uint4 vv = *(const uint4*)(Bvw + gbase + r * 64 + c8 * 8);
            *(uint4*)&sV[r * 64 + ((c8 ^ (r & 7)) * 8)] = vv;
        }
    }
#pragma unroll
    for (int p = 0; p < 16; p++) {
        int dd = p * 16 + (t >> 4), f = t & 15;
        float4 v = *(const float4*)&u[((size_t)b * DM + d0 + dd) * SL + l0 + f * 4];
        unsigned lo = (unsigned)f2bf(v.x) | ((unsigned)f2bf(v.y) << 16);
        unsigned hi = (unsigned)f2bf(v.z) | ((unsigned)f2bf(v.w) << 16);
        uint2 pk = { lo, hi };
        *(uint2*)&sU[dd * 64 + (((f >> 1) ^ (dd & 7)) * 8) + (f & 1) * 4] = pk;
    }
    __syncthreads();

    f32x4 accE[4][4];
#pragma unroll
    for (int i = 0; i < 4; i++)
#pragma unroll
        for (int j = 0; j < 4; j++) accE[i][j] = (f32x4){0.f, 0.f, 0.f, 0.f};

#pragma unroll
    for (int ks = 0; ks < 2; ks++) {
        bf16x8 af[4];
#pragma unroll
        for (int mt = 0; mt < 4; mt++) {
            int r = w * 64 + mt * 16 + m15;
            af[mt] = *(const bf16x8*)&sU[r * 64 + (((ks * 4 + g) ^ (r & 7)) * 8)];
        }
#pragma unroll
        for (int nt = 0; nt < 4; nt++) {
            int rg = nt * 16 + m15;
            bf16x8 bv = *(const bf16x8*)&sV[rg * 64 + (((ks * 4 + g) ^ (rg & 7)) * 8)];
#pragma unroll
            for (int mt = 0; mt < 4; mt++)
                accE[mt][nt] = __builtin_amdgcn_mfma_f32_16x16x32_bf16(af[mt], bv, accE[mt][nt], 0, 0, 0);
        }
    }
#pragma unroll
    for (int mt = 0; mt < 4; mt++)
#pragma unroll
        for (int nt = 0; nt < 4; nt++)
#pragma unroll
            for (int r = 0; r < 4; r++) {
                int d = d0 + w * 64 + mt * 16 + g * 4 + r;
                Ew[(((size_t)b * NC + c) * DM + d) * NS + nt * 16 + m15] = f2bf(accE[mt][nt][r]);
            }
}

// ---------- kernel 4: prefix over chunks (E -> HS in place), 8x parallel ----------
__global__ __launch_bounds__(256) void k_prefix(const float* __restrict__ A,
                                                unsigned short* __restrict__ E)
{
    int gg = blockIdx.x * 256 + threadIdx.x;     // 0 .. B*DM*32-1
    int p  = gg & 31;                            // n-pair
    int d  = (gg >> 5) & (DM - 1);
    int b  = gg >> 15;
    int n0 = p * 2;

    float a0 = A[n0 * NS + n0];
    float a1 = A[(n0 + 1) * NS + (n0 + 1)];
    v2f aT = { __powf(a0, (float)TC), __powf(a1, (float)TC) };
    v2f hs = { 0.f, 0.f };

    unsigned int* base = (unsigned int*)E + ((((size_t)b * NC) * DM + d) * NS >> 1) + p;
    const size_t cstride = ((size_t)DM * NS) >> 1;

#pragma unroll 4
    for (int c = 0; c < NC; c++) {
        unsigned int* ptr = base + (size_t)c * cstride;
        unsigned int e = *ptr;
        unsigned int sw = (unsigned)f2bf(hs.x) | ((unsigned)f2bf(hs.y) << 16);
        *ptr = sw;                                // state at START of chunk c
        hs = __builtin_elementwise_fma(aT, hs, bfpair_to_v2f(e));
    }
}

// ---------- kernel 5: y = u@G^T + HS@Wc^T via MFMA (single y write) ----------
// grid (4 dslab, NC, B). HS read direct from global (zero reuse -> no LDS).
__global__ __launch_bounds__(256) void k_y(const float* __restrict__ u,
                                           const unsigned short* __restrict__ Gw,
                                           const unsigned short* __restrict__ Wcw,
                                           const unsigned short* __restrict__ HS,
                                           float* __restrict__ y)
{
    __shared__ unsigned short sU[256 * 64];   // 32KB
    __shared__ unsigned short sG[64 * 64];    // 8KB
    __shared__ unsigned short sW[64 * 64];    // 8KB
    const int slab = blockIdx.x, c = blockIdx.y, b = blockIdx.z;
    const int d0 = slab * 256, l0 = c * TC;
    const int t = threadIdx.x, lane = t & 63, w = t >> 6, g = lane >> 4, m15 = lane & 15;

    {
        size_t gbase = ((size_t)(b * NC + c)) * 4096;
        int rr = t >> 3, c8 = t & 7;
#pragma unroll
        for (int p = 0; p < 2; p++) {
            int r = p * 32 + rr;
            uint4 gv = *(const uint4*)(Gw + gbase + r * 64 + c8 * 8);
            *(uint4*)&sG[r * 64 + ((c8 ^ (r & 7)) * 8)] = gv;
            uint4 wv = *(const uint4*)(Wcw + gbase + r * 64 + c8 * 8);
            *(uint4*)&sW[r * 64 + ((c8 ^ (r & 7)) * 8)] = wv;
        }
    }
#pragma unroll
    for (int p = 0; p < 16; p++) {
        int dd = p * 16 + (t >> 4), f = t & 15;
        float4 v = *(const float4*)&u[((size_t)b * DM + d0 + dd) * SL + l0 + f * 4];
        unsigned lo = (unsigned)f2bf(v.x) | ((unsigned)f2bf(v.y) << 16);
        unsigned hi = (unsigned)f2bf(v.z) | ((unsigned)f2bf(v.w) << 16);
        uint2 pk = { lo, hi };
        *(uint2*)&sU[dd * 64 + (((f >> 1) ^ (dd & 7)) * 8) + (f & 1) * 4] = pk;
    }
    __syncthreads();

    f32x4 acc[4][4];
#pragma unroll
    for (int i = 0; i < 4; i++)
#pragma unroll
        for (int j = 0; j < 4; j++) acc[i][j] = (f32x4){0.f, 0.f, 0.f, 0.f};

    const unsigned short* hbase = HS + (((size_t)b * NC + c) * DM + d0) * NS;

    // intra-chunk: u @ G^T
#pragma unroll
    for (int ks = 0; ks < 2; ks++) {
        bf16x8 af[4];
#pragma unroll
        for (int mt = 0; mt < 4; mt++) {
            int r = w * 64 + mt * 16 + m15;
            af[mt] = *(const bf16x8*)&sU[r * 64 + (((ks * 4 + g) ^ (r & 7)) * 8)];
        }
#pragma unroll
        for (int nt = 0; nt < 4; nt++) {
            int rg = nt * 16 + m15;
            bf16x8 bg = *(const bf16x8*)&sG[rg * 64 + (((ks * 4 + g) ^ (rg & 7)) * 8)];
#pragma unroll
            for (int mt = 0; mt < 4; mt++)
                acc[mt][nt] = __builtin_amdgcn_mfma_f32_16x16x32_bf16(af[mt], bg, acc[mt][nt], 0, 0, 0);
        }
    }
    // cross-chunk: HS @ Wc^T  (A fragments direct from global, no swizzle needed —
    // both operands use the same per-lane k-chunk map, so the k-order cancels)
#pragma unroll
    for (int ks = 0; ks < 2; ks++) {
        bf16x8 ah[4];
#pragma unroll
        for (int mt = 0; mt < 4; mt++) {
            int r = w * 64 + mt * 16 + m15;
            ah[mt] = *(const bf16x8*)(hbase + (size_t)r * NS + (ks * 4 + g) * 8);
        }
#pragma unroll
        for (int nt = 0; nt < 4; nt++) {
            int rg = nt * 16 + m15;
            bf16x8 bw = *(const bf16x8*)&sW[rg * 64 + (((ks * 4 + g) ^ (rg & 7)) * 8)];
#pragma unroll
            for (int mt = 0; mt < 4; mt++)
                acc[mt][nt] = __builtin_amdgcn_mfma_f32_16x16x32_bf16(ah[mt], bw, acc[mt][nt], 0, 0, 0);
        }
    }
#pragma unroll
    for (int mt = 0; mt < 4; mt++)
#pragma unroll
        for (int nt = 0; nt < 4; nt++)
#pragma unroll
            for (int r = 0; r < 4; r++) {
                int d = d0 + w * 64 + mt * 16 + g * 4 + r;
                int l = l0 + nt * 16 + m15;
                y[((size_t)b * DM + d) * SL + l] = acc[mt][nt][r];
            }
}

extern "C" void kernel_launch(void* const* d_in, const int* in_sizes, int n_in,
                              void* d_out, int out_size, void* d_ws, size_t ws_size,
                              hipStream_t stream) {
    const float* u = (const float*)d_in[1];
    const float* A = (const float*)d_in[2];
    const float* B = (const float*)d_in[3];
    const float* C = (const float*)d_in[4];
    float* y = (float*)d_out;

    char* base = (char*)d_ws;
    unsigned short* BuT = (unsigned short*)(base);
    unsigned short* CuT = (unsigned short*)(base + (2u << 20));
    unsigned short* BT  = (unsigned short*)(base + (4u << 20));
    unsigned short* Gw  = (unsigned short*)(base + (5u << 20));
    unsigned short* Bvw = (unsigned short*)(base + (7u << 20));
    unsigned short* Wcw = (unsigned short*)(base + (9u << 20));
    unsigned short* Ew  = (unsigned short*)(base + (11u << 20));
    unsigned short* CT  = BT + (size_t)NS * DM;

    k_prep<<<dim3(DM / 64, 2), 256, 0, stream>>>(B, C, BT, CT);
    k_proj<<<dim3(SL / 32, BATCH), 256, 0, stream>>>(u, BT, BuT, CuT);
    k_g<<<dim3(BATCH * NC), 256, 0, stream>>>(A, BuT, CuT, Gw, Bvw, Wcw);
    k_state<<<dim3(4, NC, BATCH), 256, 0, stream>>>(u, Bvw, Ew);
    k_prefix<<<dim3(BATCH * DM * 32 / 256), 256, 0, stream>>>(A, Ew);
    k_y<<<dim3(4, NC, BATCH), 256, 0, stream>>>(u, Gw, Wcw, Ew, y);
}

// Round 11
// 110.099 us; speedup vs baseline: 1.2109x; 1.2109x over previous
//
#include <hip/hip_runtime.h>
#include <hip/hip_bf16.h>
#include <string.h>

#define BATCH 8
#define DM 1024
#define NS 64
#define SL 2048
#define NC 32
#define TC 64

typedef __attribute__((ext_vector_type(8))) short bf16x8;
typedef __attribute__((ext_vector_type(4))) float f32x4;
typedef float v2f __attribute__((ext_vector_type(2)));

__device__ inline unsigned short f2bf(float f) {
    union { float f; unsigned u; } v; v.f = f;
    return (unsigned short)((v.u + 0x7fffu + ((v.u >> 16) & 1u)) >> 16);
}
__device__ inline float bf2f(unsigned short h) {
    return __uint_as_float(((unsigned)h) << 16);
}
static __device__ inline v2f bfpair_to_v2f(unsigned int p) {
    unsigned int lo = p << 16, hi = p & 0xffff0000u;
    v2f r; r.x = __uint_as_float(lo); r.y = __uint_as_float(hi); return r;
}

// ws layout (bytes):
//  BuT bf16 [B][SL][NS]      off  0MB  (2MB)
//  CuT bf16 [B][SL][NS]      off  2MB  (2MB)
//  BT  bf16 [NS][DM]         off  4MB  (128KB) ; CT right after
//  G   bf16 [B][NC][64][64]  off  5MB  (2MB)
//  Bv  bf16 [B][NC][64][64]  off  7MB  (2MB)
//  Wc  bf16 [B][NC][64][64]  off  9MB  (2MB)
//  E   bf16 [B][NC][DM][NS]  off 11MB  (32MB)   -> total 43MB

// ---------- kernel 0: transpose B,C -> BT,CT bf16 [n][d] ----------
__global__ __launch_bounds__(256) void k_prep(const float* __restrict__ Bm,
                                              const float* __restrict__ Cm,
                                              unsigned short* __restrict__ BT,
                                              unsigned short* __restrict__ CT)
{
    __shared__ float sT[64][65];
    const float* src = blockIdx.y ? Cm : Bm;
    unsigned short* dst = blockIdx.y ? CT : BT;
    const int d0 = blockIdx.x * 64, t = threadIdx.x;
    {
        int r = t >> 2, f = (t & 3) * 16;
#pragma unroll
        for (int i = 0; i < 4; i++) {
            float4 v = *(const float4*)&src[(size_t)(d0 + r) * NS + f + i * 4];
            sT[r][f + i * 4 + 0] = v.x; sT[r][f + i * 4 + 1] = v.y;
            sT[r][f + i * 4 + 2] = v.z; sT[r][f + i * 4 + 3] = v.w;
        }
    }
    __syncthreads();
    {
        int n = t >> 2, dq = (t & 3) * 16;
        unsigned pk[8];
#pragma unroll
        for (int k = 0; k < 8; k++) {
            unsigned short a = f2bf(sT[dq + 2 * k][n]);
            unsigned short bb = f2bf(sT[dq + 2 * k + 1][n]);
            pk[k] = (unsigned)a | ((unsigned)bb << 16);
        }
        uint4 v0 = { pk[0], pk[1], pk[2], pk[3] };
        uint4 v1 = { pk[4], pk[5], pk[6], pk[7] };
        *(uint4*)&dst[(size_t)n * DM + d0 + dq] = v0;
        *(uint4*)&dst[(size_t)n * DM + d0 + dq + 8] = v1;
    }
}

// ---------- kernel 1: Bu/Cu projections via MFMA, 512 threads (16 waves/CU) ----------
// grid (SL/32, B), 512 thr. out[l][n] = sum_d u[d][l] * BC[n][d]
// wave w owns n-slice wn = w*16 + m15; per iter: 2ks x 2mt x 1nt = 4 MFMA/wave.
__global__ __launch_bounds__(512) void k_proj(const float* __restrict__ u,
                                              const unsigned short* __restrict__ BC, // [128][DM]
                                              unsigned short* __restrict__ BuT,
                                              unsigned short* __restrict__ CuT)
{
    __shared__ unsigned short sA[32 * 64];   // [l][d] swz  4KB
    __shared__ unsigned short sB[128 * 64];  // [n][d] swz 16KB
    const int b = blockIdx.y, l0 = blockIdx.x * 32, t = threadIdx.x;
    const int lane = t & 63, w = t >> 6, g = lane >> 4, m15 = lane & 15;
    const int dd = t >> 3, c8 = t & 7;       // staging coords (dd 0..63)
    const int dq = dd >> 3, d7 = dd & 7;

    f32x4 acc[2];
    acc[0] = (f32x4){0.f, 0.f, 0.f, 0.f};
    acc[1] = (f32x4){0.f, 0.f, 0.f, 0.f};

#pragma unroll 1
    for (int d0 = 0; d0 < DM; d0 += 64) {
        __syncthreads();
        {   // stage A: u[d0..d0+64][l0..l0+32] -> sA[l][d] bf16 swizzled (1 float4/thread)
            float4 v = *(const float4*)&u[((size_t)b * DM + d0 + dd) * SL + l0 + c8 * 4];
            int l = c8 * 4;
            sA[(l + 0) * 64 + ((dq ^ ((l + 0) & 7)) * 8) + d7] = f2bf(v.x);
            sA[(l + 1) * 64 + ((dq ^ ((l + 1) & 7)) * 8) + d7] = f2bf(v.y);
            sA[(l + 2) * 64 + ((dq ^ ((l + 2) & 7)) * 8) + d7] = f2bf(v.z);
            sA[(l + 3) * 64 + ((dq ^ ((l + 3) & 7)) * 8) + d7] = f2bf(v.w);
        }
        // stage B: BC rows 0..127, cols d0..d0+64 (2 uint4/thread)
#pragma unroll
        for (int p = 0; p < 2; p++) {
            int idx = p * 512 + t;
            int row = idx >> 3, cc8 = idx & 7;
            uint4 v = *(const uint4*)(BC + (size_t)row * DM + d0 + cc8 * 8);
            *(uint4*)&sB[row * 64 + ((cc8 ^ (row & 7)) * 8)] = v;
        }
        __syncthreads();
#pragma unroll
        for (int ks = 0; ks < 2; ks++) {
            bf16x8 af[2], bfr;
#pragma unroll
            for (int mt = 0; mt < 2; mt++) {
                int r = mt * 16 + m15;
                af[mt] = *(const bf16x8*)&sA[r * 64 + (((ks * 4 + g) ^ (r & 7)) * 8)];
            }
            {
                int r = w * 16 + m15;
                bfr = *(const bf16x8*)&sB[r * 64 + (((ks * 4 + g) ^ (r & 7)) * 8)];
            }
#pragma unroll
            for (int mt = 0; mt < 2; mt++)
                acc[mt] = __builtin_amdgcn_mfma_f32_16x16x32_bf16(af[mt], bfr, acc[mt], 0, 0, 0);
        }
    }
    // epilogue: C[m=l][n=wn]
    {
        int wn = w * 16 + m15;
        unsigned short* dst = (wn < 64) ? BuT : CuT;
        int n = wn & 63;
#pragma unroll
        for (int mt = 0; mt < 2; mt++)
#pragma unroll
            for (int r = 0; r < 4; r++) {
                int l = l0 + mt * 16 + g * 4 + r;
                dst[((size_t)b * SL + l) * NS + n] = f2bf(acc[mt][r]);
            }
    }
}

// ---------- kernel 2: per-chunk G / Bv / Wc via power table ----------
__global__ __launch_bounds__(256) void k_g(const float* __restrict__ A,
                                           const unsigned short* __restrict__ BuT,
                                           const unsigned short* __restrict__ CuT,
                                           unsigned short* __restrict__ Gw,
                                           unsigned short* __restrict__ Bvw,
                                           unsigned short* __restrict__ Wcw)
{
    __shared__ unsigned short sCu[64 * 64];    // [l][n] linear (uniform-row reads)
    __shared__ unsigned short sBu[8 * 64 * 8]; // [q][l][8] subtiled
    __shared__ unsigned short sP[8 * 66 * 8];  // [q][dl 0..64][8] subtiled
    __shared__ unsigned short sTb[64 * 66];    // [n][l] transpose buffer (pad 66)
    const int cc = blockIdx.x, b = cc >> 5, c = cc & 31;
    const int t = threadIdx.x, lane = t & 63;
    const int l0 = c * TC;
    const size_t gbase = (size_t)cc * 4096;

    {
        const unsigned short* srcC = CuT + ((size_t)b * SL + l0) * NS;
        const unsigned short* srcB = BuT + ((size_t)b * SL + l0) * NS;
#pragma unroll
        for (int p = 0; p < 2; p++) {
            int idx = p * 256 + t;
            int r = idx >> 3, q8 = idx & 7;
            uint4 vc = *(const uint4*)(srcC + (size_t)r * NS + q8 * 8);
            *(uint4*)&sCu[r * 64 + q8 * 8] = vc;
            uint4 vb = *(const uint4*)(srcB + (size_t)r * NS + q8 * 8);
            *(uint4*)&sBu[(q8 * 64 + r) * 8] = vb;
        }
    }
    {
        int n = t & 63;
        float an = A[n * NS + n];
        int q = n >> 3, n7 = n & 7;
#pragma unroll 1
        for (int dl = (t >> 6) * 17; dl < (t >> 6) * 17 + 17 && dl <= 64; dl++)
            sP[(q * 66 + dl) * 8 + n7] = f2bf(__powf(an, (float)dl));
    }
    __syncthreads();

#pragma unroll 1
    for (int r = 0; r < 16; r++) {
        int idx = r * 256 + t;
        int l = idx >> 6;             // wave-uniform
        int lp = lane;
        int dl = l - lp;
        float acc = 0.f;
        if (dl >= 0) {
#pragma unroll
            for (int q = 0; q < 8; q++) {
                bf16x8 cu = *(const bf16x8*)&sCu[l * 64 + q * 8];
                bf16x8 bu = *(const bf16x8*)&sBu[(q * 64 + lp) * 8];
                bf16x8 pp = *(const bf16x8*)&sP[(q * 66 + dl) * 8];
#pragma unroll
                for (int j = 0; j < 8; j++)
                    acc = fmaf(bf2f((unsigned short)cu[j]) * bf2f((unsigned short)bu[j]),
                               bf2f((unsigned short)pp[j]), acc);
            }
        }
        Gw[gbase + l * 64 + lp] = (dl >= 0) ? f2bf(acc) : (unsigned short)0;
    }

#pragma unroll 1
    for (int r = 0; r < 16; r++) {
        int idx = r * 256 + t;
        int l = idx >> 6;
        int n = lane, q = n >> 3, n7 = n & 7;
        float cu = bf2f(sCu[l * 64 + n]);
        float pv = bf2f(sP[(q * 66 + (l + 1)) * 8 + n7]);
        Wcw[gbase + l * 64 + n] = f2bf(cu * pv);
    }

#pragma unroll 1
    for (int r = 0; r < 16; r++) {
        int idx = r * 256 + t;
        int l = idx >> 6;
        int n = lane, q = n >> 3, n7 = n & 7;
        float bu = bf2f(sBu[(q * 64 + l) * 8 + n7]);
        float pv = bf2f(sP[(q * 66 + (63 - l)) * 8 + n7]);
        sTb[n * 66 + l] = f2bf(bu * pv);
    }
    __syncthreads();
#pragma unroll 1
    for (int r = 0; r < 16; r++) {
        int idx = r * 256 + t;
        int n = idx >> 6;
        int l = lane;
        Bvw[gbase + n * 64 + l] = sTb[n * 66 + l];
    }
}

// ---------- kernel 3: E = u @ Bv^T via MFMA ----------
// grid (4 dslab, NC, B), 256 thr. E[d][n] = sum_l' u[d][l'] Bv[n][l']
__global__ __launch_bounds__(256) void k_state(const float* __restrict__ u,
                                               const unsigned short* __restrict__ Bvw,
                                               unsigned short* __restrict__ Ew)
{
    __shared__ unsigned short sU[256 * 64];   // 32KB
    __shared__ unsigned short sV[64 * 64];    // 8KB
    const int slab = blockIdx.x, c = blockIdx.y, b = blockIdx.z;
    const int d0 = slab * 256, l0 = c * TC;
    const int t = threadIdx.x, lane = t & 63, w = t >> 6, g = lane >> 4, m15 = lane & 15;

    {
        size_t gbase = ((size_t)(b * NC + c)) * 4096;
        int rr = t >> 3, c8 = t & 7;
#pragma unroll
        for (int p = 0; p < 2; p++) {
            int r = p * 32 + rr;
            uint4 vv = *(const uint4*)(Bvw + gbase + r * 64 + c8 * 8);
            *(uint4*)&sV[r * 64 + ((c8 ^ (r & 7)) * 8)] = vv;
        }
    }
#pragma unroll
    for (int p = 0; p < 16; p++) {
        int dd = p * 16 + (t >> 4), f = t & 15;
        float4 v = *(const float4*)&u[((size_t)b * DM + d0 + dd) * SL + l0 + f * 4];
        unsigned lo = (unsigned)f2bf(v.x) | ((unsigned)f2bf(v.y) << 16);
        unsigned hi = (unsigned)f2bf(v.z) | ((unsigned)f2bf(v.w) << 16);
        uint2 pk = { lo, hi };
        *(uint2*)&sU[dd * 64 + (((f >> 1) ^ (dd & 7)) * 8) + (f & 1) * 4] = pk;
    }
    __syncthreads();

    f32x4 accE[4][4];
#pragma unroll
    for (int i = 0; i < 4; i++)
#pragma unroll
        for (int j = 0; j < 4; j++) accE[i][j] = (f32x4){0.f, 0.f, 0.f, 0.f};

#pragma unroll
    for (int ks = 0; ks < 2; ks++) {
        bf16x8 af[4];
#pragma unroll
        for (int mt = 0; mt < 4; mt++) {
            int r = w * 64 + mt * 16 + m15;
            af[mt] = *(const bf16x8*)&sU[r * 64 + (((ks * 4 + g) ^ (r & 7)) * 8)];
        }
#pragma unroll
        for (int nt = 0; nt < 4; nt++) {
            int rg = nt * 16 + m15;
            bf16x8 bv = *(const bf16x8*)&sV[rg * 64 + (((ks * 4 + g) ^ (rg & 7)) * 8)];
#pragma unroll
            for (int mt = 0; mt < 4; mt++)
                accE[mt][nt] = __builtin_amdgcn_mfma_f32_16x16x32_bf16(af[mt], bv, accE[mt][nt], 0, 0, 0);
        }
    }
#pragma unroll
    for (int mt = 0; mt < 4; mt++)
#pragma unroll
        for (int nt = 0; nt < 4; nt++)
#pragma unroll
            for (int r = 0; r < 4; r++) {
                int d = d0 + w * 64 + mt * 16 + g * 4 + r;
                Ew[(((size_t)b * NC + c) * DM + d) * NS + nt * 16 + m15] = f2bf(accE[mt][nt][r]);
            }
}

// ---------- kernel 4: prefix over chunks (E -> HS in place), 8x parallel ----------
__global__ __launch_bounds__(256) void k_prefix(const float* __restrict__ A,
                                                unsigned short* __restrict__ E)
{
    int gg = blockIdx.x * 256 + threadIdx.x;     // 0 .. B*DM*32-1
    int p  = gg & 31;                            // n-pair
    int d  = (gg >> 5) & (DM - 1);
    int b  = gg >> 15;
    int n0 = p * 2;

    float a0 = A[n0 * NS + n0];
    float a1 = A[(n0 + 1) * NS + (n0 + 1)];
    v2f aT = { __powf(a0, (float)TC), __powf(a1, (float)TC) };
    v2f hs = { 0.f, 0.f };

    unsigned int* base = (unsigned int*)E + ((((size_t)b * NC) * DM + d) * NS >> 1) + p;
    const size_t cstride = ((size_t)DM * NS) >> 1;

#pragma unroll 4
    for (int c = 0; c < NC; c++) {
        unsigned int* ptr = base + (size_t)c * cstride;
        unsigned int e = *ptr;
        unsigned int sw = (unsigned)f2bf(hs.x) | ((unsigned)f2bf(hs.y) << 16);
        *ptr = sw;                                // state at START of chunk c
        hs = __builtin_elementwise_fma(aT, hs, bfpair_to_v2f(e));
    }
}

// ---------- kernel 5: y = u@G^T + HS@Wc^T via MFMA (single y write) ----------
// grid (4 dslab, NC, B). HS read direct from global (zero reuse -> no LDS).
__global__ __launch_bounds__(256) void k_y(const float* __restrict__ u,
                                           const unsigned short* __restrict__ Gw,
                                           const unsigned short* __restrict__ Wcw,
                                           const unsigned short* __restrict__ HS,
                                           float* __restrict__ y)
{
    __shared__ unsigned short sU[256 * 64];   // 32KB
    __shared__ unsigned short sG[64 * 64];    // 8KB
    __shared__ unsigned short sW[64 * 64];    // 8KB
    const int slab = blockIdx.x, c = blockIdx.y, b = blockIdx.z;
    const int d0 = slab * 256, l0 = c * TC;
    const int t = threadIdx.x, lane = t & 63, w = t >> 6, g = lane >> 4, m15 = lane & 15;

    {
        size_t gbase = ((size_t)(b * NC + c)) * 4096;
        int rr = t >> 3, c8 = t & 7;
#pragma unroll
        for (int p = 0; p < 2; p++) {
            int r = p * 32 + rr;
            uint4 gv = *(const uint4*)(Gw + gbase + r * 64 + c8 * 8);
            *(uint4*)&sG[r * 64 + ((c8 ^ (r & 7)) * 8)] = gv;
            uint4 wv = *(const uint4*)(Wcw + gbase + r * 64 + c8 * 8);
            *(uint4*)&sW[r * 64 + ((c8 ^ (r & 7)) * 8)] = wv;
        }
    }
#pragma unroll
    for (int p = 0; p < 16; p++) {
        int dd = p * 16 + (t >> 4), f = t & 15;
        float4 v = *(const float4*)&u[((size_t)b * DM + d0 + dd) * SL + l0 + f * 4];
        unsigned lo = (unsigned)f2bf(v.x) | ((unsigned)f2bf(v.y) << 16);
        unsigned hi = (unsigned)f2bf(v.z) | ((unsigned)f2bf(v.w) << 16);
        uint2 pk = { lo, hi };
        *(uint2*)&sU[dd * 64 + (((f >> 1) ^ (dd & 7)) * 8) + (f & 1) * 4] = pk;
    }
    __syncthreads();

    f32x4 acc[4][4];
#pragma unroll
    for (int i = 0; i < 4; i++)
#pragma unroll
        for (int j = 0; j < 4; j++) acc[i][j] = (f32x4){0.f, 0.f, 0.f, 0.f};

    const unsigned short* hbase = HS + (((size_t)b * NC + c) * DM + d0) * NS;

    // intra-chunk: u @ G^T
#pragma unroll
    for (int ks = 0; ks < 2; ks++) {
        bf16x8 af[4];
#pragma unroll
        for (int mt = 0; mt < 4; mt++) {
            int r = w * 64 + mt * 16 + m15;
            af[mt] = *(const bf16x8*)&sU[r * 64 + (((ks * 4 + g) ^ (r & 7)) * 8)];
        }
#pragma unroll
        for (int nt = 0; nt < 4; nt++) {
            int rg = nt * 16 + m15;
            bf16x8 bg = *(const bf16x8*)&sG[rg * 64 + (((ks * 4 + g) ^ (rg & 7)) * 8)];
#pragma unroll
            for (int mt = 0; mt < 4; mt++)
                acc[mt][nt] = __builtin_amdgcn_mfma_f32_16x16x32_bf16(af[mt], bg, acc[mt][nt], 0, 0, 0);
        }
    }
    // cross-chunk: HS @ Wc^T  (A fragments direct from global, zero reuse -> no LDS)
#pragma unroll
    for (int ks = 0; ks < 2; ks++) {
        bf16x8 ah[4];
#pragma unroll
        for (int mt = 0; mt < 4; mt++) {
            int r = w * 64 + mt * 16 + m15;
            ah[mt] = *(const bf16x8*)(hbase + (size_t)r * NS + (ks * 4 + g) * 8);
        }
#pragma unroll
        for (int nt = 0; nt < 4; nt++) {
            int rg = nt * 16 + m15;
            bf16x8 bw = *(const bf16x8*)&sW[rg * 64 + (((ks * 4 + g) ^ (rg & 7)) * 8)];
#pragma unroll
            for (int mt = 0; mt < 4; mt++)
                acc[mt][nt] = __builtin_amdgcn_mfma_f32_16x16x32_bf16(ah[mt], bw, acc[mt][nt], 0, 0, 0);
        }
    }
#pragma unroll
    for (int mt = 0; mt < 4; mt++)
#pragma unroll
        for (int nt = 0; nt < 4; nt++)
#pragma unroll
            for (int r = 0; r < 4; r++) {
                int d = d0 + w * 64 + mt * 16 + g * 4 + r;
                int l = l0 + nt * 16 + m15;
                y[((size_t)b * DM + d) * SL + l] = acc[mt][nt][r];
            }
}

extern "C" void kernel_launch(void* const* d_in, const int* in_sizes, int n_in,
                              void* d_out, int out_size, void* d_ws, size_t ws_size,
                              hipStream_t stream) {
    const float* u = (const float*)d_in[1];
    const float* A = (const float*)d_in[2];
    const float* B = (const float*)d_in[3];
    const float* C = (const float*)d_in[4];
    float* y = (float*)d_out;

    char* base = (char*)d_ws;
    unsigned short* BuT = (unsigned short*)(base);
    unsigned short* CuT = (unsigned short*)(base + (2u << 20));
    unsigned short* BT  = (unsigned short*)(base + (4u << 20));
    unsigned short* Gw  = (unsigned short*)(base + (5u << 20));
    unsigned short* Bvw = (unsigned short*)(base + (7u << 20));
    unsigned short* Wcw = (unsigned short*)(base + (9u << 20));
    unsigned short* Ew  = (unsigned short*)(base + (11u << 20));
    unsigned short* CT  = BT + (size_t)NS * DM;

    k_prep<<<dim3(DM / 64, 2), 256, 0, stream>>>(B, C, BT, CT);
    k_proj<<<dim3(SL / 32, BATCH), 512, 0, stream>>>(u, BT, BuT, CuT);
    k_g<<<dim3(BATCH * NC), 256, 0, stream>>>(A, BuT, CuT, Gw, Bvw, Wcw);
    k_state<<<dim3(4, NC, BATCH), 256, 0, stream>>>(u, Bvw, Ew);
    k_prefix<<<dim3(BATCH * DM * 32 / 256), 256, 0, stream>>>(A, Ew);
    k_y<<<dim3(4, NC, BATCH), 256, 0, stream>>>(u, Gw, Wcw, Ew, y);
}

// Round 12
// 103.736 us; speedup vs baseline: 1.2852x; 1.0613x over previous
//
#include <hip/hip_runtime.h>
#include <hip/hip_bf16.h>
#include <string.h>

#define BATCH 8
#define DM 1024
#define NS 64
#define SL 2048
#define NC 32
#define TC 64

typedef __attribute__((ext_vector_type(8))) short bf16x8;
typedef __attribute__((ext_vector_type(4))) float f32x4;
typedef float v2f __attribute__((ext_vector_type(2)));

__device__ inline unsigned short f2bf(float f) {
    union { float f; unsigned u; } v; v.f = f;
    return (unsigned short)((v.u + 0x7fffu + ((v.u >> 16) & 1u)) >> 16);
}
__device__ inline float bf2f(unsigned short h) {
    return __uint_as_float(((unsigned)h) << 16);
}
static __device__ inline v2f bfpair_to_v2f(unsigned int p) {
    unsigned int lo = p << 16, hi = p & 0xffff0000u;
    v2f r; r.x = __uint_as_float(lo); r.y = __uint_as_float(hi); return r;
}

// ws layout (bytes):
//  BuT bf16 [B][SL][NS]      off  0MB  (2MB)
//  CuT bf16 [B][SL][NS]      off  2MB  (2MB)
//  BT  bf16 [NS][DM]         off  4MB  (128KB) ; CT right after
//  G   bf16 [B][NC][64][64]  off  5MB  (2MB)
//  Bv  bf16 [B][NC][64][64]  off  7MB  (2MB)
//  Wc  bf16 [B][NC][64][64]  off  9MB  (2MB)
//  E   bf16 [B][NC][DM][NS]  off 11MB  (32MB)
//  Ubf bf16 [B][DM][SL]      off 44MB  (32MB)   -> total 76MB (ws >= 200MB per poison size)

// ---------- kernel 0: transpose B,C -> BT,CT bf16 [n][d] ----------
__global__ __launch_bounds__(256) void k_prep(const float* __restrict__ Bm,
                                              const float* __restrict__ Cm,
                                              unsigned short* __restrict__ BT,
                                              unsigned short* __restrict__ CT)
{
    __shared__ float sT[64][65];
    const float* src = blockIdx.y ? Cm : Bm;
    unsigned short* dst = blockIdx.y ? CT : BT;
    const int d0 = blockIdx.x * 64, t = threadIdx.x;
    {
        int r = t >> 2, f = (t & 3) * 16;
#pragma unroll
        for (int i = 0; i < 4; i++) {
            float4 v = *(const float4*)&src[(size_t)(d0 + r) * NS + f + i * 4];
            sT[r][f + i * 4 + 0] = v.x; sT[r][f + i * 4 + 1] = v.y;
            sT[r][f + i * 4 + 2] = v.z; sT[r][f + i * 4 + 3] = v.w;
        }
    }
    __syncthreads();
    {
        int n = t >> 2, dq = (t & 3) * 16;
        unsigned pk[8];
#pragma unroll
        for (int k = 0; k < 8; k++) {
            unsigned short a = f2bf(sT[dq + 2 * k][n]);
            unsigned short bb = f2bf(sT[dq + 2 * k + 1][n]);
            pk[k] = (unsigned)a | ((unsigned)bb << 16);
        }
        uint4 v0 = { pk[0], pk[1], pk[2], pk[3] };
        uint4 v1 = { pk[4], pk[5], pk[6], pk[7] };
        *(uint4*)&dst[(size_t)n * DM + d0 + dq] = v0;
        *(uint4*)&dst[(size_t)n * DM + d0 + dq + 8] = v1;
    }
}

// ---------- kernel 1: Bu/Cu projections via MFMA, 512 threads; also emits Ubf ----------
// grid (SL/32, B), 512 thr. out[l][n] = sum_d u[d][l] * BC[n][d]
__global__ __launch_bounds__(512) void k_proj(const float* __restrict__ u,
                                              const unsigned short* __restrict__ BC, // [128][DM]
                                              unsigned short* __restrict__ BuT,
                                              unsigned short* __restrict__ CuT,
                                              unsigned short* __restrict__ Ubf)
{
    __shared__ unsigned short sA[32 * 64];   // [l][d] swz  4KB
    __shared__ unsigned short sB[128 * 64];  // [n][d] swz 16KB
    const int b = blockIdx.y, l0 = blockIdx.x * 32, t = threadIdx.x;
    const int lane = t & 63, w = t >> 6, g = lane >> 4, m15 = lane & 15;
    const int dd = t >> 3, c8 = t & 7;       // staging coords (dd 0..63)
    const int dq = dd >> 3, d7 = dd & 7;

    f32x4 acc[2];
    acc[0] = (f32x4){0.f, 0.f, 0.f, 0.f};
    acc[1] = (f32x4){0.f, 0.f, 0.f, 0.f};

#pragma unroll 1
    for (int d0 = 0; d0 < DM; d0 += 64) {
        __syncthreads();
        {   // stage A: u[d0..d0+64][l0..l0+32] -> sA[l][d] bf16 swizzled; also emit Ubf
            float4 v = *(const float4*)&u[((size_t)b * DM + d0 + dd) * SL + l0 + c8 * 4];
            unsigned short b0 = f2bf(v.x), b1 = f2bf(v.y), b2 = f2bf(v.z), b3 = f2bf(v.w);
            int l = c8 * 4;
            sA[(l + 0) * 64 + ((dq ^ ((l + 0) & 7)) * 8) + d7] = b0;
            sA[(l + 1) * 64 + ((dq ^ ((l + 1) & 7)) * 8) + d7] = b1;
            sA[(l + 2) * 64 + ((dq ^ ((l + 2) & 7)) * 8) + d7] = b2;
            sA[(l + 3) * 64 + ((dq ^ ((l + 3) & 7)) * 8) + d7] = b3;
            uint2 pk = { (unsigned)b0 | ((unsigned)b1 << 16),
                         (unsigned)b2 | ((unsigned)b3 << 16) };
            *(uint2*)(Ubf + ((size_t)b * DM + d0 + dd) * SL + l0 + c8 * 4) = pk;
        }
        // stage B: BC rows 0..127, cols d0..d0+64 (2 uint4/thread)
#pragma unroll
        for (int p = 0; p < 2; p++) {
            int idx = p * 512 + t;
            int row = idx >> 3, cc8 = idx & 7;
            uint4 v = *(const uint4*)(BC + (size_t)row * DM + d0 + cc8 * 8);
            *(uint4*)&sB[row * 64 + ((cc8 ^ (row & 7)) * 8)] = v;
        }
        __syncthreads();
#pragma unroll
        for (int ks = 0; ks < 2; ks++) {
            bf16x8 af[2], bfr;
#pragma unroll
            for (int mt = 0; mt < 2; mt++) {
                int r = mt * 16 + m15;
                af[mt] = *(const bf16x8*)&sA[r * 64 + (((ks * 4 + g) ^ (r & 7)) * 8)];
            }
            {
                int r = w * 16 + m15;
                bfr = *(const bf16x8*)&sB[r * 64 + (((ks * 4 + g) ^ (r & 7)) * 8)];
            }
#pragma unroll
            for (int mt = 0; mt < 2; mt++)
                acc[mt] = __builtin_amdgcn_mfma_f32_16x16x32_bf16(af[mt], bfr, acc[mt], 0, 0, 0);
        }
    }
    // epilogue: C[m=l][n=wn]
    {
        int wn = w * 16 + m15;
        unsigned short* dst = (wn < 64) ? BuT : CuT;
        int n = wn & 63;
#pragma unroll
        for (int mt = 0; mt < 2; mt++)
#pragma unroll
            for (int r = 0; r < 4; r++) {
                int l = l0 + mt * 16 + g * 4 + r;
                dst[((size_t)b * SL + l) * NS + n] = f2bf(acc[mt][r]);
            }
    }
}

// ---------- kernel 2: per-chunk G / Bv / Wc via power table, 2 blocks/chunk ----------
// gy=0: G rounds 0..7 + Wc.  gy=1: G rounds 8..15 + Bv.
__global__ __launch_bounds__(256) void k_g(const float* __restrict__ A,
                                           const unsigned short* __restrict__ BuT,
                                           const unsigned short* __restrict__ CuT,
                                           unsigned short* __restrict__ Gw,
                                           unsigned short* __restrict__ Bvw,
                                           unsigned short* __restrict__ Wcw)
{
    __shared__ unsigned short sCu[64 * 64];    // [l][n] linear (uniform-row reads)
    __shared__ unsigned short sBu[8 * 64 * 8]; // [q][l][8] subtiled
    __shared__ unsigned short sP[8 * 66 * 8];  // [q][dl 0..64][8] subtiled
    __shared__ unsigned short sTb[64 * 66];    // [n][l] transpose buffer (pad 66)
    const int cc = blockIdx.x, b = cc >> 5, c = cc & 31;
    const int gy = blockIdx.y;
    const int t = threadIdx.x, lane = t & 63;
    const int l0 = c * TC;
    const size_t gbase = (size_t)cc * 4096;

    {
        const unsigned short* srcC = CuT + ((size_t)b * SL + l0) * NS;
        const unsigned short* srcB = BuT + ((size_t)b * SL + l0) * NS;
#pragma unroll
        for (int p = 0; p < 2; p++) {
            int idx = p * 256 + t;
            int r = idx >> 3, q8 = idx & 7;
            uint4 vc = *(const uint4*)(srcC + (size_t)r * NS + q8 * 8);
            *(uint4*)&sCu[r * 64 + q8 * 8] = vc;
            uint4 vb = *(const uint4*)(srcB + (size_t)r * NS + q8 * 8);
            *(uint4*)&sBu[(q8 * 64 + r) * 8] = vb;
        }
    }
    {
        int n = t & 63;
        float an = A[n * NS + n];
        int q = n >> 3, n7 = n & 7;
#pragma unroll 1
        for (int dl = (t >> 6) * 17; dl < (t >> 6) * 17 + 17 && dl <= 64; dl++)
            sP[(q * 66 + dl) * 8 + n7] = f2bf(__powf(an, (float)dl));
    }
    __syncthreads();

    // ---- G: 8 rounds per block, wave-uniform l, lane = lp ----
#pragma unroll 1
    for (int r = gy * 8; r < gy * 8 + 8; r++) {
        int idx = r * 256 + t;
        int l = idx >> 6;             // wave-uniform
        int lp = lane;
        int dl = l - lp;
        float acc = 0.f;
        if (dl >= 0) {
#pragma unroll
            for (int q = 0; q < 8; q++) {
                bf16x8 cu = *(const bf16x8*)&sCu[l * 64 + q * 8];
                bf16x8 bu = *(const bf16x8*)&sBu[(q * 64 + lp) * 8];
                bf16x8 pp = *(const bf16x8*)&sP[(q * 66 + dl) * 8];
#pragma unroll
                for (int j = 0; j < 8; j++)
                    acc = fmaf(bf2f((unsigned short)cu[j]) * bf2f((unsigned short)bu[j]),
                               bf2f((unsigned short)pp[j]), acc);
            }
        }
        Gw[gbase + l * 64 + lp] = (dl >= 0) ? f2bf(acc) : (unsigned short)0;
    }

    if (gy == 0) {
        // ---- Wc[l][n] = Cu[l][n] * P[l+1][n] ----
#pragma unroll 1
        for (int r = 0; r < 16; r++) {
            int idx = r * 256 + t;
            int l = idx >> 6;
            int n = lane, q = n >> 3, n7 = n & 7;
            float cu = bf2f(sCu[l * 64 + n]);
            float pv = bf2f(sP[(q * 66 + (l + 1)) * 8 + n7]);
            Wcw[gbase + l * 64 + n] = f2bf(cu * pv);
        }
    } else {
        // ---- Bv: elementwise into transpose buffer, then coalesced out ----
#pragma unroll 1
        for (int r = 0; r < 16; r++) {
            int idx = r * 256 + t;
            int l = idx >> 6;
            int n = lane, q = n >> 3, n7 = n & 7;
            float bu = bf2f(sBu[(q * 64 + l) * 8 + n7]);
            float pv = bf2f(sP[(q * 66 + (63 - l)) * 8 + n7]);
            sTb[n * 66 + l] = f2bf(bu * pv);
        }
        __syncthreads();
#pragma unroll 1
        for (int r = 0; r < 16; r++) {
            int idx = r * 256 + t;
            int n = idx >> 6;
            int l = lane;
            Bvw[gbase + n * 64 + l] = sTb[n * 66 + l];
        }
    }
}

// ---------- kernel 3: E = u @ Bv^T via MFMA (u from bf16 cache) ----------
// grid (4 dslab, NC, B), 256 thr. E[d][n] = sum_l' u[d][l'] Bv[n][l']
__global__ __launch_bounds__(256) void k_state(const unsigned short* __restrict__ Ubf,
                                               const unsigned short* __restrict__ Bvw,
                                               unsigned short* __restrict__ Ew)
{
    __shared__ unsigned short sU[256 * 64];   // 32KB
    __shared__ unsigned short sV[64 * 64];    // 8KB
    const int slab = blockIdx.x, c = blockIdx.y, b = blockIdx.z;
    const int d0 = slab * 256, l0 = c * TC;
    const int t = threadIdx.x, lane = t & 63, w = t >> 6, g = lane >> 4, m15 = lane & 15;

    {
        size_t gbase = ((size_t)(b * NC + c)) * 4096;
        int rr = t >> 3, c8 = t & 7;
#pragma unroll
        for (int p = 0; p < 2; p++) {
            int r = p * 32 + rr;
            uint4 vv = *(const uint4*)(Bvw + gbase + r * 64 + c8 * 8);
            *(uint4*)&sV[r * 64 + ((c8 ^ (r & 7)) * 8)] = vv;
        }
    }
    {   // stage u tile from bf16 cache: pure uint4 copies, swizzled
        const unsigned short* usrc = Ubf + ((size_t)b * DM + d0) * SL + l0;
#pragma unroll
        for (int p = 0; p < 8; p++) {
            int idx = p * 256 + t;
            int dd = idx >> 3, q8 = idx & 7;
            uint4 v = *(const uint4*)(usrc + (size_t)dd * SL + q8 * 8);
            *(uint4*)&sU[dd * 64 + ((q8 ^ (dd & 7)) * 8)] = v;
        }
    }
    __syncthreads();

    f32x4 accE[4][4];
#pragma unroll
    for (int i = 0; i < 4; i++)
#pragma unroll
        for (int j = 0; j < 4; j++) accE[i][j] = (f32x4){0.f, 0.f, 0.f, 0.f};

#pragma unroll
    for (int ks = 0; ks < 2; ks++) {
        bf16x8 af[4];
#pragma unroll
        for (int mt = 0; mt < 4; mt++) {
            int r = w * 64 + mt * 16 + m15;
            af[mt] = *(const bf16x8*)&sU[r * 64 + (((ks * 4 + g) ^ (r & 7)) * 8)];
        }
#pragma unroll
        for (int nt = 0; nt < 4; nt++) {
            int rg = nt * 16 + m15;
            bf16x8 bv = *(const bf16x8*)&sV[rg * 64 + (((ks * 4 + g) ^ (rg & 7)) * 8)];
#pragma unroll
            for (int mt = 0; mt < 4; mt++)
                accE[mt][nt] = __builtin_amdgcn_mfma_f32_16x16x32_bf16(af[mt], bv, accE[mt][nt], 0, 0, 0);
        }
    }
#pragma unroll
    for (int mt = 0; mt < 4; mt++)
#pragma unroll
        for (int nt = 0; nt < 4; nt++)
#pragma unroll
            for (int r = 0; r < 4; r++) {
                int d = d0 + w * 64 + mt * 16 + g * 4 + r;
                Ew[(((size_t)b * NC + c) * DM + d) * NS + nt * 16 + m15] = f2bf(accE[mt][nt][r]);
            }
}

// ---------- kernel 4: prefix over chunks (E -> HS in place), 8x parallel ----------
__global__ __launch_bounds__(256) void k_prefix(const float* __restrict__ A,
                                                unsigned short* __restrict__ E)
{
    int gg = blockIdx.x * 256 + threadIdx.x;     // 0 .. B*DM*32-1
    int p  = gg & 31;                            // n-pair
    int d  = (gg >> 5) & (DM - 1);
    int b  = gg >> 15;
    int n0 = p * 2;

    float a0 = A[n0 * NS + n0];
    float a1 = A[(n0 + 1) * NS + (n0 + 1)];
    v2f aT = { __powf(a0, (float)TC), __powf(a1, (float)TC) };
    v2f hs = { 0.f, 0.f };

    unsigned int* base = (unsigned int*)E + ((((size_t)b * NC) * DM + d) * NS >> 1) + p;
    const size_t cstride = ((size_t)DM * NS) >> 1;

#pragma unroll 4
    for (int c = 0; c < NC; c++) {
        unsigned int* ptr = base + (size_t)c * cstride;
        unsigned int e = *ptr;
        unsigned int sw = (unsigned)f2bf(hs.x) | ((unsigned)f2bf(hs.y) << 16);
        *ptr = sw;                                // state at START of chunk c
        hs = __builtin_elementwise_fma(aT, hs, bfpair_to_v2f(e));
    }
}

// ---------- kernel 5: y = u@G^T + HS@Wc^T via MFMA (u from bf16 cache) ----------
// grid (4 dslab, NC, B). HS read direct from global (zero reuse -> no LDS).
__global__ __launch_bounds__(256) void k_y(const unsigned short* __restrict__ Ubf,
                                           const unsigned short* __restrict__ Gw,
                                           const unsigned short* __restrict__ Wcw,
                                           const unsigned short* __restrict__ HS,
                                           float* __restrict__ y)
{
    __shared__ unsigned short sU[256 * 64];   // 32KB
    __shared__ unsigned short sG[64 * 64];    // 8KB
    __shared__ unsigned short sW[64 * 64];    // 8KB
    const int slab = blockIdx.x, c = blockIdx.y, b = blockIdx.z;
    const int d0 = slab * 256, l0 = c * TC;
    const int t = threadIdx.x, lane = t & 63, w = t >> 6, g = lane >> 4, m15 = lane & 15;

    {
        size_t gbase = ((size_t)(b * NC + c)) * 4096;
        int rr = t >> 3, c8 = t & 7;
#pragma unroll
        for (int p = 0; p < 2; p++) {
            int r = p * 32 + rr;
            uint4 gv = *(const uint4*)(Gw + gbase + r * 64 + c8 * 8);
            *(uint4*)&sG[r * 64 + ((c8 ^ (r & 7)) * 8)] = gv;
            uint4 wv = *(const uint4*)(Wcw + gbase + r * 64 + c8 * 8);
            *(uint4*)&sW[r * 64 + ((c8 ^ (r & 7)) * 8)] = wv;
        }
    }
    {   // stage u tile from bf16 cache
        const unsigned short* usrc = Ubf + ((size_t)b * DM + d0) * SL + l0;
#pragma unroll
        for (int p = 0; p < 8; p++) {
            int idx = p * 256 + t;
            int dd = idx >> 3, q8 = idx & 7;
            uint4 v = *(const uint4*)(usrc + (size_t)dd * SL + q8 * 8);
            *(uint4*)&sU[dd * 64 + ((q8 ^ (dd & 7)) * 8)] = v;
        }
    }
    __syncthreads();

    f32x4 acc[4][4];
#pragma unroll
    for (int i = 0; i < 4; i++)
#pragma unroll
        for (int j = 0; j < 4; j++) acc[i][j] = (f32x4){0.f, 0.f, 0.f, 0.f};

    const unsigned short* hbase = HS + (((size_t)b * NC + c) * DM + d0) * NS;

    // intra-chunk: u @ G^T
#pragma unroll
    for (int ks = 0; ks < 2; ks++) {
        bf16x8 af[4];
#pragma unroll
        for (int mt = 0; mt < 4; mt++) {
            int r = w * 64 + mt * 16 + m15;
            af[mt] = *(const bf16x8*)&sU[r * 64 + (((ks * 4 + g) ^ (r & 7)) * 8)];
        }
#pragma unroll
        for (int nt = 0; nt < 4; nt++) {
            int rg = nt * 16 + m15;
            bf16x8 bg = *(const bf16x8*)&sG[rg * 64 + (((ks * 4 + g) ^ (rg & 7)) * 8)];
#pragma unroll
            for (int mt = 0; mt < 4; mt++)
                acc[mt][nt] = __builtin_amdgcn_mfma_f32_16x16x32_bf16(af[mt], bg, acc[mt][nt], 0, 0, 0);
        }
    }
    // cross-chunk: HS @ Wc^T  (A fragments direct from global, zero reuse -> no LDS)
#pragma unroll
    for (int ks = 0; ks < 2; ks++) {
        bf16x8 ah[4];
#pragma unroll
        for (int mt = 0; mt < 4; mt++) {
            int r = w * 64 + mt * 16 + m15;
            ah[mt] = *(const bf16x8*)(hbase + (size_t)r * NS + (ks * 4 + g) * 8);
        }
#pragma unroll
        for (int nt = 0; nt < 4; nt++) {
            int rg = nt * 16 + m15;
            bf16x8 bw = *(const bf16x8*)&sW[rg * 64 + (((ks * 4 + g) ^ (rg & 7)) * 8)];
#pragma unroll
            for (int mt = 0; mt < 4; mt++)
                acc[mt][nt] = __builtin_amdgcn_mfma_f32_16x16x32_bf16(ah[mt], bw, acc[mt][nt], 0, 0, 0);
        }
    }
#pragma unroll
    for (int mt = 0; mt < 4; mt++)
#pragma unroll
        for (int nt = 0; nt < 4; nt++)
#pragma unroll
            for (int r = 0; r < 4; r++) {
                int d = d0 + w * 64 + mt * 16 + g * 4 + r;
                int l = l0 + nt * 16 + m15;
                y[((size_t)b * DM + d) * SL + l] = acc[mt][nt][r];
            }
}

extern "C" void kernel_launch(void* const* d_in, const int* in_sizes, int n_in,
                              void* d_out, int out_size, void* d_ws, size_t ws_size,
                              hipStream_t stream) {
    const float* u = (const float*)d_in[1];
    const float* A = (const float*)d_in[2];
    const float* B = (const float*)d_in[3];
    const float* C = (const float*)d_in[4];
    float* y = (float*)d_out;

    char* base = (char*)d_ws;
    unsigned short* BuT = (unsigned short*)(base);
    unsigned short* CuT = (unsigned short*)(base + (2u << 20));
    unsigned short* BT  = (unsigned short*)(base + (4u << 20));
    unsigned short* Gw  = (unsigned short*)(base + (5u << 20));
    unsigned short* Bvw = (unsigned short*)(base + (7u << 20));
    unsigned short* Wcw = (unsigned short*)(base + (9u << 20));
    unsigned short* Ew  = (unsigned short*)(base + (11u << 20));
    unsigned short* Ubf = (unsigned short*)(base + (44u << 20));
    unsigned short* CT  = BT + (size_t)NS * DM;

    k_prep<<<dim3(DM / 64, 2), 256, 0, stream>>>(B, C, BT, CT);
    k_proj<<<dim3(SL / 32, BATCH), 512, 0, stream>>>(u, BT, BuT, CuT, Ubf);
    k_g<<<dim3(BATCH * NC, 2), 256, 0, stream>>>(A, BuT, CuT, Gw, Bvw, Wcw);
    k_state<<<dim3(4, NC, BATCH), 256, 0, stream>>>(Ubf, Bvw, Ew);
    k_prefix<<<dim3(BATCH * DM * 32 / 256), 256, 0, stream>>>(A, Ew);
    k_y<<<dim3(4, NC, BATCH), 256, 0, stream>>>(Ubf, Gw, Wcw, Ew, y);
}